// Round 1
// baseline (396.191 us; speedup 1.0000x reference)
//
#include <hip/hip_runtime.h>
#include <cfloat>

#define NBINS 25

// Pass 1: wave-per-row softmax-confidence + argmax + binned accumulation.
// ws layout: [0..24]=counts, [25..49]=sum_conf, [50..74]=sum_acc (floats).
__launch_bounds__(256, 8)
__global__ void ece_pass1(const float* __restrict__ logits,
                          const int* __restrict__ labels,
                          float* __restrict__ ws, int n) {
    __shared__ float s_cnt[NBINS], s_conf[NBINS], s_acc[NBINS];
    if (threadIdx.x < NBINS) {
        s_cnt[threadIdx.x]  = 0.f;
        s_conf[threadIdx.x] = 0.f;
        s_acc[threadIdx.x]  = 0.f;
    }
    __syncthreads();

    const int lane   = threadIdx.x & 63;
    const int gwave  = (int)((blockIdx.x * blockDim.x + threadIdx.x) >> 6);
    const int nwaves = (int)((gridDim.x * blockDim.x) >> 6);

    for (int row = gwave; row < n; row += nwaves) {
        const float4* rp = reinterpret_cast<const float4*>(logits) + (size_t)row * 25;
        float a0 = -FLT_MAX, a1 = -FLT_MAX, a2 = -FLT_MAX, a3 = -FLT_MAX;
        if (lane < 25) {
            float4 v = rp[lane];
            a0 = v.x; a1 = v.y; a2 = v.z; a3 = v.w;
        }
        // local argmax (first-occurrence tiebreak => keep smallest index)
        float m = a0; int mi = lane * 4;
        if (a1 > m) { m = a1; mi = lane * 4 + 1; }
        if (a2 > m) { m = a2; mi = lane * 4 + 2; }
        if (a3 > m) { m = a3; mi = lane * 4 + 3; }
        // wave butterfly argmax-reduce
#pragma unroll
        for (int off = 32; off; off >>= 1) {
            float om = __shfl_xor(m, off);
            int   oi = __shfl_xor(mi, off);
            if (om > m || (om == m && oi < mi)) { m = om; mi = oi; }
        }
        // sum of exp(l - max)
        float s = 0.f;
        if (lane < 25) {
            s = __expf(a0 - m) + __expf(a1 - m) + __expf(a2 - m) + __expf(a3 - m);
        }
#pragma unroll
        for (int off = 32; off; off >>= 1) s += __shfl_xor(s, off);

        if (lane == 0) {
            float conf = 1.0f / s;                         // exp(max-max)/sum
            int bin = (int)ceilf(conf * (float)NBINS) - 1; // (i/25,(i+1)/25]
            bin = min(max(bin, 0), NBINS - 1);
            float acc = (mi == labels[row]) ? 1.f : 0.f;
            atomicAdd(&s_cnt[bin], 1.f);
            atomicAdd(&s_conf[bin], conf);
            atomicAdd(&s_acc[bin], acc);
        }
    }
    __syncthreads();
    if (threadIdx.x < NBINS) {
        atomicAdd(&ws[threadIdx.x],             s_cnt[threadIdx.x]);
        atomicAdd(&ws[NBINS + threadIdx.x],     s_conf[threadIdx.x]);
        atomicAdd(&ws[2 * NBINS + threadIdx.x], s_acc[threadIdx.x]);
    }
}

// Pass 2: single wave computes the 25-term ECE sum.
__global__ void ece_final(const float* __restrict__ ws, float* __restrict__ out, float n) {
    int t = threadIdx.x;
    float term = 0.f;
    if (t < NBINS) {
        float cnt = ws[t];
        float sc  = ws[NBINS + t];
        float sa  = ws[2 * NBINS + t];
        if (cnt > 0.f) {
            float inv = 1.f / cnt; // cnt >= 1 here, matches max(counts,1)
            term = fabsf(sc * inv - sa * inv) * (cnt / n);
        }
    }
#pragma unroll
    for (int off = 32; off; off >>= 1) term += __shfl_xor(term, off);
    if (t == 0) out[0] = term;
}

extern "C" void kernel_launch(void* const* d_in, const int* in_sizes, int n_in,
                              void* d_out, int out_size, void* d_ws, size_t ws_size,
                              hipStream_t stream) {
    const float* logits = (const float*)d_in[0];
    const int*   labels = (const int*)d_in[1];
    float* ws  = (float*)d_ws;
    float* out = (float*)d_out;
    const int n = in_sizes[1]; // number of rows / labels

    hipMemsetAsync(ws, 0, 3 * NBINS * sizeof(float), stream);

    const int block = 256;
    const int grid  = 2048; // capped grid-stride: limits global atomics, keeps BW saturated
    ece_pass1<<<grid, block, 0, stream>>>(logits, labels, ws, n);
    ece_final<<<1, 64, 0, stream>>>(ws, out, (float)n);
}

// Round 2
// 312.189 us; speedup vs baseline: 1.2691x; 1.2691x over previous
//
#include <hip/hip_runtime.h>
#include <cfloat>

#define NBINS 25

// Pass 1: 4 lanes per row => 16 rows per wave-iteration.
// ws layout: [0..24]=counts, [25..49]=sum_conf, [50..74]=sum_acc (floats).
__launch_bounds__(256, 8)
__global__ void ece_pass1(const float* __restrict__ logits,
                          const int* __restrict__ labels,
                          float* __restrict__ ws, int n) {
    __shared__ float s_cnt[NBINS], s_conf[NBINS], s_acc[NBINS];
    if (threadIdx.x < NBINS) {
        s_cnt[threadIdx.x]  = 0.f;
        s_conf[threadIdx.x] = 0.f;
        s_acc[threadIdx.x]  = 0.f;
    }
    __syncthreads();

    const int lane = threadIdx.x & 63;
    const int j    = lane & 3;   // sublane within 4-lane group
    const int g    = lane >> 2;  // group 0..15 -> row within batch of 16
    const int wid  = (int)((blockIdx.x * blockDim.x + threadIdx.x) >> 6);
    const int nw   = (int)((gridDim.x * blockDim.x) >> 6);

    for (int base = wid * 16; base < n; base += nw * 16) {
        const int row = base + g;
        const bool rowok = row < n;
        const float4* rp = reinterpret_cast<const float4*>(logits) + (size_t)row * 25;

        // Each lane loads float4s q = j, j+4, ..., (<25). j==0 gets 7, others 6.
        float4 v[7];
#pragma unroll
        for (int k = 0; k < 6; ++k) {
            v[k] = rowok ? rp[j + 4 * k]
                         : make_float4(-FLT_MAX, -FLT_MAX, -FLT_MAX, -FLT_MAX);
        }
        v[6] = (rowok && j == 0) ? rp[24]
                                 : make_float4(-FLT_MAX, -FLT_MAX, -FLT_MAX, -FLT_MAX);

        // Per-lane argmax over its elements, ascending index order (first-occurrence ties).
        float m = -FLT_MAX; int mi = 0;
#pragma unroll
        for (int k = 0; k < 7; ++k) {
            const int q = j + 4 * k;
            const int idx = 4 * q;
            if (v[k].x > m) { m = v[k].x; mi = idx; }
            if (v[k].y > m) { m = v[k].y; mi = idx + 1; }
            if (v[k].z > m) { m = v[k].z; mi = idx + 2; }
            if (v[k].w > m) { m = v[k].w; mi = idx + 3; }
        }
        // Group-of-4 argmax reduce (xor 1, 2); smaller index wins ties.
#pragma unroll
        for (int off = 1; off <= 2; off <<= 1) {
            float om = __shfl_xor(m, off);
            int   oi = __shfl_xor(mi, off);
            if (om > m || (om == m && oi < mi)) { m = om; mi = oi; }
        }

        // Sum of exp(v - m) over this lane's elements, then group reduce.
        float s = 0.f;
#pragma unroll
        for (int k = 0; k < 7; ++k) {
            const int q = j + 4 * k;
            if (q < 25) {
                s += __expf(v[k].x - m) + __expf(v[k].y - m) +
                     __expf(v[k].z - m) + __expf(v[k].w - m);
            }
        }
#pragma unroll
        for (int off = 1; off <= 2; off <<= 1) s += __shfl_xor(s, off);

        if (rowok && j == 0) {
            float conf = 1.0f / s;                         // exp(max-max)/sum
            int bin = (int)ceilf(conf * (float)NBINS) - 1; // (i/25,(i+1)/25]
            bin = min(max(bin, 0), NBINS - 1);
            float acc = (mi == labels[row]) ? 1.f : 0.f;
            atomicAdd(&s_cnt[bin], 1.f);
            atomicAdd(&s_conf[bin], conf);
            atomicAdd(&s_acc[bin], acc);
        }
    }
    __syncthreads();
    if (threadIdx.x < NBINS) {
        atomicAdd(&ws[threadIdx.x],             s_cnt[threadIdx.x]);
        atomicAdd(&ws[NBINS + threadIdx.x],     s_conf[threadIdx.x]);
        atomicAdd(&ws[2 * NBINS + threadIdx.x], s_acc[threadIdx.x]);
    }
}

// Pass 2: single wave computes the 25-term ECE sum.
__global__ void ece_final(const float* __restrict__ ws, float* __restrict__ out, float n) {
    int t = threadIdx.x;
    float term = 0.f;
    if (t < NBINS) {
        float cnt = ws[t];
        float sc  = ws[NBINS + t];
        float sa  = ws[2 * NBINS + t];
        if (cnt > 0.f) {
            float inv = 1.f / cnt; // cnt >= 1 here, matches max(counts,1)
            term = fabsf(sc * inv - sa * inv) * (cnt / n);
        }
    }
#pragma unroll
    for (int off = 32; off; off >>= 1) term += __shfl_xor(term, off);
    if (t == 0) out[0] = term;
}

extern "C" void kernel_launch(void* const* d_in, const int* in_sizes, int n_in,
                              void* d_out, int out_size, void* d_ws, size_t ws_size,
                              hipStream_t stream) {
    const float* logits = (const float*)d_in[0];
    const int*   labels = (const int*)d_in[1];
    float* ws  = (float*)d_ws;
    float* out = (float*)d_out;
    const int n = in_sizes[1]; // number of rows / labels

    hipMemsetAsync(ws, 0, 3 * NBINS * sizeof(float), stream);

    const int block = 256;
    const int grid  = 2048; // capped grid-stride: limits global atomics, keeps BW saturated
    ece_pass1<<<grid, block, 0, stream>>>(logits, labels, ws, n);
    ece_final<<<1, 64, 0, stream>>>(ws, out, (float)n);
}